// Round 1
// 100.398 us; speedup vs baseline: 1.0005x; 1.0005x over previous
//
#include <hip/hip_runtime.h>
#include <math.h>

// ClipStyleContrastiveLoss on MI355X (gfx950).
// Math reduction (BETA=1 => imp==neg):
//   E = exp(L/t), exp(2L/t) = E^2
//   S1[i] = rowsum(E)[i] + colsum(E)[i] - 2*E[i,i]
//   S2[i] = rowsum(E^2)[i] + colsum(E^2)[i] - 2*E[i,i]^2
//   reweight = N*S2/S1 ; Ng = (reweight - tau*N*pos)/(1-tau), clamped at N*e^{-1/t}
//   loss = mean over B rows of log((pos+Ng+eps)/pos)
//
// R5: timed graph is dominated by two 256-MiB harness workspace poisons
// (~41 us each) we cannot control; shave the controllable ~17 us:
//   - drop the 4-B hipMemsetAsync dispatch (pass1 zeroes d_out)
//   - 32 rows/block (8 per wave) -> S=128 stripes, colP 8.4 MB -> 4.2 MB
//     (halves partial write AND pass2 re-read), grid (4,128) = 2 blocks/CU.

#define THREADS    256
// 1/(TEMPERATURE*ln2) = 2/ln2 : exp(x/t) = exp2(x*EXP_SCALE)
#define EXP_SCALE  2.885390081777927f

__global__ __launch_bounds__(THREADS) void pass1_kernel(
    const float* __restrict__ L,
    float2* __restrict__ rowP,   // [4][B]   (E,E2) row sums per col-stripe
    float2* __restrict__ colP,   // [S][B]   (E,E2) col partials, S = B/32
    float* __restrict__ out,
    int B)
{
    __shared__ float ldsE [4][1024];   // 16 KB
    __shared__ float ldsE2[4][1024];   // 16 KB

    const int t       = threadIdx.x;
    const int lane    = t & 63;
    const int wave    = t >> 6;
    const int x       = blockIdx.x;            // col stripe (1024 cols)
    const int s       = blockIdx.y;            // row stripe (32 rows)
    const int row0    = s * 32 + wave * 8;     // wave's 8 rows
    const int colBase = x * 1024 + lane * 4;

    // Zero the scalar output here instead of a separate 4-B memset dispatch.
    // pass2 runs in a later dispatch, so ordering/visibility is guaranteed.
    if ((x | s | t) == 0) out[0] = 0.f;

    float cE[16], cE2[16];
#pragma unroll
    for (int k = 0; k < 16; ++k) { cE[k] = 0.f; cE2[k] = 0.f; }

    // Two groups of 4 rows: same register/load-pipeline shape as the proven
    // 16-row kernel (4 independent float4 loads in flight per row, deferred
    // shuffle reduction per group), iterated twice.
#pragma unroll
    for (int g = 0; g < 2; ++g) {
        float rs[4], rs2[4];
#pragma unroll
        for (int r = 0; r < 4; ++r) {
            const float* Lr = L + (size_t)(row0 + g * 4 + r) * B + colBase;
            float a = 0.f, b = 0.f;
#pragma unroll
            for (int j = 0; j < 4; ++j) {
                const float4 v = *reinterpret_cast<const float4*>(Lr + j * 256);
                float e0 = exp2f(v.x * EXP_SCALE);
                float e1 = exp2f(v.y * EXP_SCALE);
                float e2 = exp2f(v.z * EXP_SCALE);
                float e3 = exp2f(v.w * EXP_SCALE);
                float q0 = e0 * e0, q1 = e1 * e1, q2 = e2 * e2, q3 = e3 * e3;
                cE [j*4+0] += e0; cE [j*4+1] += e1; cE [j*4+2] += e2; cE [j*4+3] += e3;
                cE2[j*4+0] += q0; cE2[j*4+1] += q1; cE2[j*4+2] += q2; cE2[j*4+3] += q3;
                a += (e0 + e1) + (e2 + e3);
                b += (q0 + q1) + (q2 + q3);
            }
            rs[r] = a; rs2[r] = b;
        }

        // Deferred row reductions (out of the load loop — no per-row dep barrier).
#pragma unroll
        for (int r = 0; r < 4; ++r) {
            float a = rs[r], b = rs2[r];
#pragma unroll
            for (int off = 32; off > 0; off >>= 1) {
                a += __shfl_down(a, off, 64);
                b += __shfl_down(b, off, 64);
            }
            if (lane == 0) rowP[(size_t)x * B + row0 + g * 4 + r] = make_float2(a, b);
        }
    }

    // Cross-wave col combine: each wave dumps its partials (float4 writes),
    // then all threads sum the 4 waves per column (stride-1 reads, conflict-free).
#pragma unroll
    for (int j = 0; j < 4; ++j) {
        *reinterpret_cast<float4*>(&ldsE [wave][lane * 4 + j * 256]) =
            make_float4(cE [j*4+0], cE [j*4+1], cE [j*4+2], cE [j*4+3]);
        *reinterpret_cast<float4*>(&ldsE2[wave][lane * 4 + j * 256]) =
            make_float4(cE2[j*4+0], cE2[j*4+1], cE2[j*4+2], cE2[j*4+3]);
    }
    __syncthreads();

#pragma unroll
    for (int m = 0; m < 4; ++m) {
        const int c = t + m * 256;
        float se  = (ldsE [0][c] + ldsE [1][c]) + (ldsE [2][c] + ldsE [3][c]);
        float se2 = (ldsE2[0][c] + ldsE2[1][c]) + (ldsE2[2][c] + ldsE2[3][c]);
        colP[(size_t)s * B + x * 1024 + c] = make_float2(se, se2);   // coalesced 8B
    }
}

// Merge S=128 stripe partials + row sums + diag -> loss; 256 blocks x 16 cols.
__global__ __launch_bounds__(THREADS) void pass2_kernel(
    const float* __restrict__ L,
    const float2* __restrict__ rowP,
    const float2* __restrict__ colP,
    float* __restrict__ out,
    int B, int S)
{
    const int t    = threadIdx.x;
    const int c    = t & 15;
    const int g    = t >> 4;
    const int base = blockIdx.x * 16;

    float se = 0.f, se2 = 0.f;
    for (int k = g; k < S; k += 16) {
        const float2 v = colP[(size_t)k * B + base + c];
        se += v.x; se2 += v.y;
    }
    __shared__ float2 part[16][17];
    part[g][c] = make_float2(se, se2);
    __syncthreads();

    if (t < 16) {
        float colE = 0.f, colE2 = 0.f;
#pragma unroll
        for (int gg = 0; gg < 16; ++gg) {
            colE  += part[gg][t].x;
            colE2 += part[gg][t].y;
        }
        const int i = base + t;
        float rowE = 0.f, rowE2 = 0.f;
#pragma unroll
        for (int x = 0; x < 4; ++x) {
            const float2 rv = rowP[(size_t)x * B + i];
            rowE += rv.x; rowE2 += rv.y;
        }
        const float Nf = (float)(2 * B - 2);
        float dg = L[(size_t)i * B + i];
        float pe = exp2f(dg * EXP_SCALE);
        float S1 = rowE  + colE  - 2.f * pe;
        float S2 = rowE2 + colE2 - 2.f * (pe * pe);
        float rw = Nf * (S2 / S1);                        // N * sum(neg^2)/sum(neg)
        float Ng = (rw - 0.1f * Nf * pe) * (1.f / 0.9f);  // (-tau*N*pos + rw)/(1-tau)
        Ng = fmaxf(Ng, Nf * 0.13533528323661270f);        // N * e^{-1/t}
        float loss = logf((pe + Ng + 1e-8f) / pe);
#pragma unroll
        for (int off = 8; off > 0; off >>= 1) loss += __shfl_down(loss, off, 16);
        if (t == 0) atomicAdd(out, loss / (float)B);
    }
}

extern "C" void kernel_launch(void* const* d_in, const int* in_sizes, int n_in,
                              void* d_out, int out_size, void* d_ws, size_t ws_size,
                              hipStream_t stream) {
    const float* L = (const float*)d_in[0];
    int B = 1;
    while ((long long)B * B < (long long)in_sizes[0]) B <<= 1;  // B = 4096
    const int S = B / 32;                                       // 128 row stripes

    float2* rowP = (float2*)d_ws;                   // 4*B float2 = 128 KB
    float2* colP = rowP + (size_t)4 * B;            // S*B float2 = 4.2 MB

    dim3 grid1(4, B / 32);                          // (4, 128) = 512 blocks
    pass1_kernel<<<grid1, THREADS, 0, stream>>>(L, rowP, colP, (float*)d_out, B);
    pass2_kernel<<<B / 16, THREADS, 0, stream>>>(L, rowP, colP, (float*)d_out, B, S);
}

// Round 2
// 97.526 us; speedup vs baseline: 1.0299x; 1.0294x over previous
//
#include <hip/hip_runtime.h>
#include <math.h>

// ClipStyleContrastiveLoss on MI355X (gfx950).
// Math reduction (BETA=1 => imp==neg):
//   E = exp(L/t), exp(2L/t) = E^2
//   S1[i] = rowsum(E)[i] + colsum(E)[i] - 2*E[i,i]
//   S2[i] = rowsum(E^2)[i] + colsum(E^2)[i] - 2*E[i,i]^2
//   reweight = N*S2/S1 ; Ng = (reweight - tau*N*pos)/(1-tau), clamped at N*e^{-1/t}
//   loss = mean over B rows of log((pos+Ng+eps)/pos)
//
// R6: R1's flat result revealed pass1 is occupancy-sensitive: 512 blocks
// (8 waves/CU) lost exactly what the traffic cut saved. Re-split tiles to
// 32 rows x 512 cols -> grid (8,128) = 1024 blocks (16 waves/CU, R0 level)
// while KEEPING S=128 (colP 4 MB, half of R0). Pass2 folds rowP into the
// parallel partial loop. No memset dispatch (pass1 zeroes out).

#define THREADS    256
// 1/(TEMPERATURE*ln2) = 2/ln2 : exp(x/t) = exp2(x*EXP_SCALE)
#define EXP_SCALE  2.885390081777927f

__global__ __launch_bounds__(THREADS) void pass1_kernel(
    const float* __restrict__ L,
    float2* __restrict__ rowP,   // [8][B]   (E,E2) row sums per col-stripe
    float2* __restrict__ colP,   // [S][B]   (E,E2) col partials, S = B/32
    float* __restrict__ out,
    int B)
{
    __shared__ float ldsE [4][512];   // 8 KB
    __shared__ float ldsE2[4][512];   // 8 KB

    const int t       = threadIdx.x;
    const int lane    = t & 63;
    const int wave    = t >> 6;
    const int x       = blockIdx.x;            // col stripe (512 cols)
    const int s       = blockIdx.y;            // row stripe (32 rows)
    const int row0    = s * 32 + wave * 8;     // wave's 8 rows
    const int colBase = x * 512 + lane * 4;

    // Zero the scalar output here instead of a separate 4-B memset dispatch.
    if ((x | s | t) == 0) out[0] = 0.f;

    float cE[8], cE2[8], rs[8], rs2[8];
#pragma unroll
    for (int k = 0; k < 8; ++k) { cE[k] = 0.f; cE2[k] = 0.f; }

    // 8 rows/wave, 2 float4 loads per row; deferred row reductions keep the
    // load loop free of cross-lane dependencies (proven R0 pipeline shape).
#pragma unroll
    for (int r = 0; r < 8; ++r) {
        const float* Lr = L + (size_t)(row0 + r) * B + colBase;
        float a = 0.f, b = 0.f;
#pragma unroll
        for (int j = 0; j < 2; ++j) {
            const float4 v = *reinterpret_cast<const float4*>(Lr + j * 256);
            float e0 = exp2f(v.x * EXP_SCALE);
            float e1 = exp2f(v.y * EXP_SCALE);
            float e2 = exp2f(v.z * EXP_SCALE);
            float e3 = exp2f(v.w * EXP_SCALE);
            float q0 = e0 * e0, q1 = e1 * e1, q2 = e2 * e2, q3 = e3 * e3;
            cE [j*4+0] += e0; cE [j*4+1] += e1; cE [j*4+2] += e2; cE [j*4+3] += e3;
            cE2[j*4+0] += q0; cE2[j*4+1] += q1; cE2[j*4+2] += q2; cE2[j*4+3] += q3;
            a += (e0 + e1) + (e2 + e3);
            b += (q0 + q1) + (q2 + q3);
        }
        rs[r] = a; rs2[r] = b;
    }

    // Deferred row reductions (after all loads issued).
#pragma unroll
    for (int r = 0; r < 8; ++r) {
        float a = rs[r], b = rs2[r];
#pragma unroll
        for (int off = 32; off > 0; off >>= 1) {
            a += __shfl_down(a, off, 64);
            b += __shfl_down(b, off, 64);
        }
        if (lane == 0) rowP[(size_t)x * B + row0 + r] = make_float2(a, b);
    }

    // Cross-wave col combine: each wave dumps its partials (float4 writes),
    // then all threads sum the 4 waves per column (stride-1 reads, conflict-free).
#pragma unroll
    for (int j = 0; j < 2; ++j) {
        *reinterpret_cast<float4*>(&ldsE [wave][lane * 4 + j * 256]) =
            make_float4(cE [j*4+0], cE [j*4+1], cE [j*4+2], cE [j*4+3]);
        *reinterpret_cast<float4*>(&ldsE2[wave][lane * 4 + j * 256]) =
            make_float4(cE2[j*4+0], cE2[j*4+1], cE2[j*4+2], cE2[j*4+3]);
    }
    __syncthreads();

#pragma unroll
    for (int m = 0; m < 2; ++m) {
        const int c = t + m * 256;
        float se  = (ldsE [0][c] + ldsE [1][c]) + (ldsE [2][c] + ldsE [3][c]);
        float se2 = (ldsE2[0][c] + ldsE2[1][c]) + (ldsE2[2][c] + ldsE2[3][c]);
        colP[(size_t)s * B + x * 512 + c] = make_float2(se, se2);   // coalesced 8B
    }
}

// Merge S=128 stripe partials + 8 rowP stripes + diag -> loss; 256 blocks x 16 cols.
// Since S1/S2 add row- and col-sums, rowP is folded into the same partial loop.
__global__ __launch_bounds__(THREADS) void pass2_kernel(
    const float* __restrict__ L,
    const float2* __restrict__ rowP,
    const float2* __restrict__ colP,
    float* __restrict__ out,
    int B, int S)
{
    const int t    = threadIdx.x;
    const int c    = t & 15;
    const int g    = t >> 4;
    const int base = blockIdx.x * 16;

    float se = 0.f, se2 = 0.f;
    if (g < 8) {                                   // 8 rowP stripes
        const float2 rv = rowP[(size_t)g * B + base + c];
        se = rv.x; se2 = rv.y;
    }
    for (int k = g; k < S; k += 16) {
        const float2 v = colP[(size_t)k * B + base + c];
        se += v.x; se2 += v.y;
    }
    __shared__ float2 part[16][17];
    part[g][c] = make_float2(se, se2);
    __syncthreads();

    if (t < 16) {
        float sumE = 0.f, sumE2 = 0.f;
#pragma unroll
        for (int gg = 0; gg < 16; ++gg) {
            sumE  += part[gg][t].x;
            sumE2 += part[gg][t].y;
        }
        const int i = base + t;
        const float Nf = (float)(2 * B - 2);
        float dg = L[(size_t)i * B + i];
        float pe = exp2f(dg * EXP_SCALE);
        float S1 = sumE  - 2.f * pe;               // rowE + colE - 2*E[ii]
        float S2 = sumE2 - 2.f * (pe * pe);
        float rw = Nf * (S2 / S1);                        // N * sum(neg^2)/sum(neg)
        float Ng = (rw - 0.1f * Nf * pe) * (1.f / 0.9f);  // (-tau*N*pos + rw)/(1-tau)
        Ng = fmaxf(Ng, Nf * 0.13533528323661270f);        // N * e^{-1/t}
        float loss = logf((pe + Ng + 1e-8f) / pe);
#pragma unroll
        for (int off = 8; off > 0; off >>= 1) loss += __shfl_down(loss, off, 16);
        if (t == 0) atomicAdd(out, loss / (float)B);
    }
}

extern "C" void kernel_launch(void* const* d_in, const int* in_sizes, int n_in,
                              void* d_out, int out_size, void* d_ws, size_t ws_size,
                              hipStream_t stream) {
    const float* L = (const float*)d_in[0];
    int B = 1;
    while ((long long)B * B < (long long)in_sizes[0]) B <<= 1;  // B = 4096
    const int S = B / 32;                                       // 128 row stripes

    float2* rowP = (float2*)d_ws;                   // 8*B float2 = 256 KB
    float2* colP = rowP + (size_t)8 * B;            // S*B float2 = 4.2 MB

    dim3 grid1(8, B / 32);                          // (8, 128) = 1024 blocks
    pass1_kernel<<<grid1, THREADS, 0, stream>>>(L, rowP, colP, (float*)d_out, B);
    pass2_kernel<<<B / 16, THREADS, 0, stream>>>(L, rowP, colP, (float*)d_out, B, S);
}